// Round 12
// baseline (336.605 us; speedup 1.0000x reference)
//
#include <hip/hip_runtime.h>
#include <stdint.h>

typedef unsigned short u16;
typedef __bf16 bf16x8 __attribute__((ext_vector_type(8)));
typedef float f32x4 __attribute__((ext_vector_type(4)));
typedef u16 u16x4 __attribute__((ext_vector_type(4)));

#define MFMA16(a, b, c) __builtin_amdgcn_mfma_f32_16x16x32_bf16((a), (b), (c), 0, 0, 0)

__device__ __forceinline__ u16 f2bf(float f) {
  uint32_t u = __builtin_bit_cast(uint32_t, f);
  u += 0x7FFFu + ((u >> 16) & 1u);  // RNE
  return (u16)(u >> 16);
}
__device__ __forceinline__ bf16x8 cvt8(f32x4 lo, f32x4 hi) {
  union { u16 u[8]; bf16x8 v; } r;
#pragma unroll
  for (int j = 0; j < 4; j++) { r.u[j] = f2bf(lo[j]); r.u[4 + j] = f2bf(hi[j]); }
  return r.v;
}
// async global->LDS, 16B per lane. LDS dest = wave-uniform base + lane*16.
__device__ __forceinline__ void gld_lds16(const void* g, void* l) {
  __builtin_amdgcn_global_load_lds(
      (const __attribute__((address_space(1))) uint32_t*)g,
      (__attribute__((address_space(3))) uint32_t*)l, 16, 0, 0);
}

// ---------------------------------------------------------------------------
// Fused prep (R7, proven): weight-interp vectorized 8 samples/thread.
// ---------------------------------------------------------------------------
__global__ void prep_kernel(const float* __restrict__ x, const float* __restrict__ cpq,
                            const float* __restrict__ cpk, const float* __restrict__ cpv,
                            const float* __restrict__ cpo, u16* __restrict__ xb,
                            u16* __restrict__ Wqkv, u16* __restrict__ Wo,
                            int n, double factor) {
  int blk = blockIdx.x;
  if (blk < 8192) {
    int base = (blk * 256 + threadIdx.x) * 8;
    int w = base >> 22;
    int i = base & 4194303;
    const float* cp = (w == 0) ? cpq : (w == 1) ? cpk : (w == 2) ? cpv : cpo;
    union { u16 u[8]; bf16x8 v; } r;
#pragma unroll
    for (int s = 0; s < 8; s++) {
      double u = (double)(i + s) * factor;
      int i0 = (int)u;
      if (i0 > n - 2) i0 = n - 2;
      float fr = (float)(u - (double)i0);
      float f0 = cp[i0], f1 = cp[i0 + 1];
      r.u[s] = f2bf(f0 + fr * (f1 - f0));
    }
    if (w < 3) *(bf16x8*)(Wqkv + base) = r.v;
    else       *(bf16x8*)(Wo + i) = r.v;
  } else {
    size_t i = ((size_t)(blk - 8192) * 256 + threadIdx.x) * 8;
    const f32x4* p = (const f32x4*)(x + i);
    *(bf16x8*)(xb + i) = cvt8(p[0], p[1]);
  }
}

// ---------------------------------------------------------------------------
// R12: QKV projection, 256x256x64 8-phase (quadrant) pipelined GEMM.
// Rationale: the R0 128x128 kernel measures 44% MfmaUtil = 98% of its
// LDS-feed cap (cap = MFMA_cyc/LDS_cyc; model validated on R0/R3/m201).
// Escaping needs per-wave 128x64 tiles; at 128KiB LDS (1 blk/CU) that only
// pays with a FINE-GRAINED phase schedule (m196: coarse split hurts -- the
// R2-R4 failures). Ledger (hand-verified, FIFO traced):
//  waves: wm=wave&1 -> rows wm*128; wn=wave>>1 -> cols wn*64. acc[8][4].
//  A-half(rh) = rows {rh*64+[0,64)} u {128+rh*64+[0,64)}  (16 KB, 2 ld/thr)
//  B-half(ch) = n-rows with (n>>5)&1==ch                   (16 KB, 2 ld/thr)
//  tile X (buf c=X&1), 4 phases, each: [stage 1 half][vmcnt(6)][ds_reads]
//    [setprio 16 MFMA][s_barrier+sched_barrier]:
//   ph1 (rh0,ch0): reads A0(8xb128)+B0(4); stages A-II(X+1)->buf c^1
//   ph2 (rh0,ch1): reads B1(4), af held;   stages A-I (X+2)->buf c
//   ph3 (rh1,ch1): reads A1(8), bf1 held;  stages B-I (X+2)->buf c
//   ph4 (rh1,ch0): no reads (bf0+af held); stages B-II(X+2)->buf c
//  Stage targets freed previous phase (barrier-sep). vmcnt(6) retires the
//  pair issued 3 phases ago -> each needed half retired by its STAGING wave
//  >=1 barrier before any READER's ds_read (cross-wave visibility). Needs
//  are 4-7 phases old. Never drained to 0 until the peeled tail.
//  Prologue: 7 pairs [A-I0,B-I0,B-II0,A-II0,A-I1,B-I1,B-II1], vmcnt(10).
//  Tail: X=30 waits 6/4/2/2 (no stage ph2-4); X=31 waits 0/-/-/-.
// Accumulation order per acc cell identical to R0 -> bit-identical output.
// Grid (24,16): XCD = bx%8 -> 3 B-panels (3MB) L2-resident (R3-validated).
// ---------------------------------------------------------------------------
__global__ __launch_bounds__(512, 2)
void gemm_qkv(const u16* __restrict__ A, const u16* __restrict__ B,
              u16* __restrict__ oQ, u16* __restrict__ oK, u16* __restrict__ oV) {
  __shared__ __align__(16) u16 As[2 * 256 * 64];   // 65536 B
  __shared__ __align__(16) u16 Bs[2 * 256 * 64];   // 65536 B
  const int tid = threadIdx.x;
  const int wave = tid >> 6, lane = tid & 63, quad = lane >> 4, l16 = lane & 15;
  const int wm = wave & 1, wn = wave >> 1;
  const int m0 = blockIdx.y * 256, n0 = blockIdx.x * 256;

  // stage addressing (pre-swizzled global src, LINEAR LDS dest)
  const int rq = wave * 8 + (lane >> 3);
  const uint32_t gcS = (uint32_t)((((lane & 7) ^ (rq & 7))) * 16);
  const uint32_t aSrcB = (uint32_t)(m0 + rq) * 4096u + gcS;        // +rh*0x40000+u*0x80000+kb
  const int sT0 = (wave >= 4) ? 1 : 0;
  const uint32_t bSrcB = (uint32_t)(n0 + rq) * 4096u + (uint32_t)sT0 * 131072u + gcS;  // +ch*0x20000+u*0x80000+kb
  const int aBase = wave * 1024 + lane * 16;                        // +rh*8192+u*16384
  const int bDBase = aBase + sT0 * 4096;                            // +ch*4096+u*16384

  // ds_read bases (swizzled; chunk = (t*4+quad)^(l16&7), t=1 => ^64)
  const int swzR = (quad ^ (l16 & 7)) * 16;
  const int rbA = (wm * 128 + l16) * 128 + swzR;   // +rh*8192+i*2048
  const int rbB = (wn * 64 + l16) * 128 + swzR;    // +ch*4096+j*2048

  const char* Ab = (const char*)A;
  const char* Bb = (const char*)B;
  char* AsB = (char*)As;
  char* BsB = (char*)Bs;

  f32x4 acc[8][4];
  const f32x4 fz = {0.f, 0.f, 0.f, 0.f};
#pragma unroll
  for (int i = 0; i < 8; i++)
#pragma unroll
    for (int j = 0; j < 4; j++) acc[i][j] = fz;

  bf16x8 af[4][2], bf0[2][2], bf1[2][2];

#define VMW_(N) asm volatile("s_waitcnt vmcnt(" #N ")" ::: "memory")
#define VMW(N) VMW_(N)
#define NOW ((void)0)
#define BARR do { __builtin_amdgcn_s_barrier(); __builtin_amdgcn_sched_barrier(0); } while (0)

#define ST_A(RH, C, Y) do { uint32_t kb = (uint32_t)(Y) * 128u;               \
    gld_lds16(Ab + (size_t)(aSrcB + (RH)*0x40000u + kb),                      \
              AsB + (C)*32768 + aBase + (RH)*8192);                           \
    gld_lds16(Ab + (size_t)(aSrcB + (RH)*0x40000u + 0x80000u + kb),           \
              AsB + (C)*32768 + aBase + (RH)*8192 + 16384); } while (0)

#define ST_B(CH, C, Y) do { uint32_t kb = (uint32_t)(Y) * 128u;               \
    gld_lds16(Bb + (size_t)(bSrcB + (CH)*0x20000u + kb),                      \
              BsB + (C)*32768 + bDBase + (CH)*4096);                          \
    gld_lds16(Bb + (size_t)(bSrcB + (CH)*0x20000u + 0x80000u + kb),           \
              BsB + (C)*32768 + bDBase + (CH)*4096 + 16384); } while (0)

#define RD_A(C, RH)                                                           \
  _Pragma("unroll") for (int i = 0; i < 4; i++) {                             \
    int o = rbA + (RH)*8192 + i*2048;                                         \
    af[i][0] = *(const bf16x8*)(AsB + (C)*32768 + o);                         \
    af[i][1] = *(const bf16x8*)(AsB + (C)*32768 + (o ^ 64)); }

#define RD_B(C, CH, BF)                                                       \
  _Pragma("unroll") for (int j = 0; j < 2; j++) {                             \
    int o = rbB + (CH)*4096 + j*2048;                                         \
    BF[j][0] = *(const bf16x8*)(BsB + (C)*32768 + o);                         \
    BF[j][1] = *(const bf16x8*)(BsB + (C)*32768 + (o ^ 64)); }

#define MM(R0, C0, BF) do { __builtin_amdgcn_s_setprio(1);                    \
  _Pragma("unroll") for (int i = 0; i < 4; i++)                               \
    _Pragma("unroll") for (int j = 0; j < 2; j++) {                           \
      acc[(R0)+i][(C0)+j] = MFMA16(af[i][0], BF[j][0], acc[(R0)+i][(C0)+j]);  \
      acc[(R0)+i][(C0)+j] = MFMA16(af[i][1], BF[j][1], acc[(R0)+i][(C0)+j]);  \
    }                                                                         \
  __builtin_amdgcn_s_setprio(0); } while (0)

// one tile = 4 phases; ST*=stage-enable (literal), WT*=wait statement
#define TILE(X, C, ST1, WT1, ST2, WT2, ST3, WT3, ST4, WT4) do {               \
    if (ST1) ST_A(1, (C) ^ 1, (X) + 1);                                       \
    WT1; RD_B((C), 0, bf0); RD_A((C), 0); MM(0, 0, bf0); BARR;                \
    if (ST2) ST_A(0, (C), (X) + 2);                                           \
    WT2; RD_B((C), 1, bf1); MM(0, 2, bf1); BARR;                              \
    if (ST3) ST_B(0, (C), (X) + 2);                                           \
    WT3; RD_A((C), 1); MM(4, 2, bf1); BARR;                                   \
    if (ST4) ST_B(1, (C), (X) + 2);                                           \
    WT4; MM(4, 0, bf0); BARR;                                                 \
  } while (0)

  // prologue: 7 half-tile pairs, FIFO [A-I0,B-I0,B-II0,A-II0,A-I1,B-I1,B-II1]
  ST_A(0, 0, 0); ST_B(0, 0, 0); ST_B(1, 0, 0); ST_A(1, 0, 0);
  ST_A(0, 1, 1); ST_B(0, 1, 1); ST_B(1, 1, 1);
  VMW(10);  // retire A-I(0), B-I(0)
  BARR;

  for (int X = 0; X < 30; X += 2) {
    TILE(X, 0, 1, VMW(6), 1, VMW(6), 1, VMW(6), 1, VMW(6));
    TILE(X + 1, 1, 1, VMW(6), 1, VMW(6), 1, VMW(6), 1, VMW(6));
  }
  TILE(30, 0, 1, VMW(6), 0, VMW(4), 0, VMW(2), 0, VMW(2));
  TILE(31, 1, 0, VMW(0), 0, NOW, 0, NOW, 0, NOW);

#undef TILE
#undef MM
#undef RD_B
#undef RD_A
#undef ST_B
#undef ST_A

  // epilogue: C frag layout col=lane&15 (n), row=quad*4+reg (m). Verified R0.
  const float qscale = 0.08838834764831845f;  // folded into Q
#pragma unroll
  for (int jj = 0; jj < 4; jj++) {
    int nb = n0 + wn * 64 + jj * 16;
    int sel = nb >> 11;                      // 0=Q 1=K 2=V (block-uniform)
    int h = (nb >> 7) & 15;
    int d = (nb & 127) + l16;
#pragma unroll
    for (int ii = 0; ii < 8; ii++) {
      int mrow = m0 + wm * 128 + ii * 16 + quad * 4;
      int bq = mrow >> 11, srow = mrow & 2047;
      if (sel == 2) {
        u16x4 pk = {f2bf(acc[ii][jj][0]), f2bf(acc[ii][jj][1]),
                    f2bf(acc[ii][jj][2]), f2bf(acc[ii][jj][3])};
        *(u16x4*)&oV[(size_t)(((bq << 4) + h) * 128 + d) * 2048 + srow] = pk;
      } else if (sel == 0) {
        int base = ((bq << 4) + h) * 2048;
#pragma unroll
        for (int r = 0; r < 4; r++)
          oQ[(size_t)(base + srow + r) * 128 + d] = f2bf(acc[ii][jj][r] * qscale);
      } else {
        int base = ((bq << 4) + h) * 2048;
#pragma unroll
        for (int r = 0; r < 4; r++)
          oK[(size_t)(base + srow + r) * 128 + d] = f2bf(acc[ii][jj][r]);
      }
    }
  }
}

// ---------------------------------------------------------------------------
// C[M,N] = A[M,2048] @ B[N,2048]^T, bf16 in, f32 acc. 128x128 tile, BK=64.
// PROVEN R0 body; used for the output projection (MODE 1).
// ---------------------------------------------------------------------------
template <int MODE>
__global__ __launch_bounds__(256, 3)
void gemm_bt(const u16* __restrict__ A, const u16* __restrict__ B,
             u16* __restrict__ oQ, u16* __restrict__ oK, u16* __restrict__ oV,
             float* __restrict__ oC) {
  constexpr int KD = 2048;
  __shared__ __align__(16) u16 As[128 * 64];
  __shared__ __align__(16) u16 Bs[128 * 64];
  const int tid = threadIdx.x;
  const int wave = tid >> 6, lane = tid & 63, quad = lane >> 4, l16 = lane & 15;
  const int wm = wave & 1, wn = wave >> 1;
  const int m0 = blockIdx.y * 128, n0 = blockIdx.x * 128;

  size_t aoff[4], boff[4];
  int lslot[4];
#pragma unroll
  for (int b = 0; b < 4; b++) {
    int s = wave * 256 + b * 64 + lane;
    int r = s >> 3, c = s & 7, gc = c ^ (r & 7);
    lslot[b] = s * 16;
    aoff[b] = (size_t)(m0 + r) * (KD * 2) + gc * 16;
    boff[b] = (size_t)(n0 + r) * (KD * 2) + gc * 16;
  }
  const char* Ab = (const char*)A;
  const char* Bb = (const char*)B;
  char* AsB = (char*)As;
  char* BsB = (char*)Bs;

  f32x4 acc[4][4];
  const f32x4 fz = {0.f, 0.f, 0.f, 0.f};
#pragma unroll
  for (int i = 0; i < 4; i++)
#pragma unroll
    for (int j = 0; j < 4; j++) acc[i][j] = fz;

  for (int kt = 0; kt < KD / 64; ++kt) {
    if (kt) __syncthreads();
#pragma unroll
    for (int b = 0; b < 4; b++) {
      gld_lds16(Ab + aoff[b], AsB + lslot[b]);
      gld_lds16(Bb + boff[b], BsB + lslot[b]);
      aoff[b] += 128;
      boff[b] += 128;
    }
    __syncthreads();
#pragma unroll
    for (int t = 0; t < 2; t++) {
      bf16x8 af[4], bfb[4];
#pragma unroll
      for (int i = 0; i < 4; i++) {
        int row = wm * 64 + i * 16 + l16;
        int ch = (t * 4 + quad) ^ (row & 7);
        af[i] = *(const bf16x8*)(AsB + row * 128 + ch * 16);
      }
#pragma unroll
      for (int j = 0; j < 4; j++) {
        int row = wn * 64 + j * 16 + l16;
        int ch = (t * 4 + quad) ^ (row & 7);
        bfb[j] = *(const bf16x8*)(BsB + row * 128 + ch * 16);
      }
#pragma unroll
      for (int i = 0; i < 4; i++)
#pragma unroll
        for (int j = 0; j < 4; j++) acc[i][j] = MFMA16(af[i], bfb[j], acc[i][j]);
    }
  }

  if (MODE == 0) {
    const float qscale = 0.08838834764831845f;
#pragma unroll
    for (int j = 0; j < 4; j++) {
      int nb = n0 + wn * 64 + j * 16;
      int sel = nb >> 11;
      int h = (nb >> 7) & 15;
      int d = (nb & 127) + l16;
#pragma unroll
      for (int i = 0; i < 4; i++) {
        int mrow = m0 + wm * 64 + i * 16 + quad * 4;
        int bq = mrow >> 11, srow = mrow & 2047;
        if (sel == 2) {
          u16x4 pk = {f2bf(acc[i][j][0]), f2bf(acc[i][j][1]),
                      f2bf(acc[i][j][2]), f2bf(acc[i][j][3])};
          *(u16x4*)&oV[(size_t)(((bq << 4) + h) * 128 + d) * 2048 + srow] = pk;
        } else if (sel == 0) {
          int base = ((bq << 4) + h) * 2048;
#pragma unroll
          for (int r = 0; r < 4; r++)
            oQ[(size_t)(base + srow + r) * 128 + d] = f2bf(acc[i][j][r] * qscale);
        } else {
          int base = ((bq << 4) + h) * 2048;
#pragma unroll
          for (int r = 0; r < 4; r++)
            oK[(size_t)(base + srow + r) * 128 + d] = f2bf(acc[i][j][r]);
        }
      }
    }
  } else {
#pragma unroll
    for (int j = 0; j < 4; j++) {
      int col = n0 + wn * 64 + j * 16 + l16;
#pragma unroll
      for (int i = 0; i < 4; i++) {
        int mrow = m0 + wm * 64 + i * 16 + quad * 4;
#pragma unroll
        for (int r = 0; r < 4; r++) oC[(size_t)(mrow + r) * 2048 + col] = acc[i][j][r];
      }
    }
  }
}

// ---------------------------------------------------------------------------
// Causal flash attention -- R10-proven body (staged K/V, R7 XCD head-group,
// swizzled zero-pad Ps). Unchanged.
// ---------------------------------------------------------------------------
__global__ __launch_bounds__(256, 2)
void flash_attn(const u16* __restrict__ Q, const u16* __restrict__ Kg,
                const u16* __restrict__ Vt, u16* __restrict__ attn) {
  __shared__ __align__(16) u16 Ks[64 * 128];
  __shared__ __align__(16) u16 Vs[128 * 64];
  __shared__ __align__(16) u16 Ps[128 * 64];
  const int tid = threadIdx.x;
  const int wave = tid >> 6, lane = tid & 63, quad = lane >> 4, l16 = lane & 15;
  const int L = blockIdx.x;
  const int g = L >> 3;
  const int s4 = g >> 2;
  const int qt = (s4 < 8) ? s4 : 23 - s4;
  const int bh = (L & 7) * 4 + (g & 3);
  const int q0 = qt * 128;
  const u16* Qb = Q + (size_t)bh * 2048 * 128;
  const u16* Kb = Kg + (size_t)bh * 2048 * 128;
  const u16* Vb = Vt + (size_t)bh * 128 * 2048;

  bf16x8 qf[2][4];
#pragma unroll
  for (int i = 0; i < 2; i++) {
    int row = q0 + wave * 32 + i * 16 + l16;
#pragma unroll
    for (int t = 0; t < 4; t++)
      qf[i][t] = *(const bf16x8*)(Qb + (size_t)row * 128 + t * 32 + quad * 8);
  }

  f32x4 o_acc[2][8];
  const f32x4 fz = {0.f, 0.f, 0.f, 0.f};
#pragma unroll
  for (int i = 0; i < 2; i++)
#pragma unroll
    for (int j = 0; j < 8; j++) o_acc[i][j] = fz;
  float l_i[2] = {0.f, 0.f};

  int koff[4], voff[4], lslot[4];
#pragma unroll
  for (int b = 0; b < 4; b++) {
    int s = wave * 256 + b * 64 + lane;
    lslot[b] = s * 16;
    {
      int r = s >> 4, c = s & 15;
      int gc = (c & 8) | ((c & 7) ^ (r & 7));
      koff[b] = r * 256 + gc * 16;
    }
    {
      int r = s >> 3, c = s & 7;
      int gc = c ^ (r & 7);
      voff[b] = r * 4096 + gc * 16;
    }
  }
  const char* KbB = (const char*)Kb;
  const char* VbB = (const char*)Vb;
  char* KsB = (char*)Ks;
  char* VsB = (char*)Vs;
  char* PsB = (char*)Ps;
  const int ps_swz = l16 & 7;

  const int ktmax = 2 * qt + 1;

  for (int kt = 0; kt <= ktmax; ++kt) {
    const int k0 = kt * 64;
    if (kt) __syncthreads();
#pragma unroll
    for (int b = 0; b < 4; b++) {
      gld_lds16(KbB + (size_t)k0 * 256 + koff[b], KsB + lslot[b]);
      gld_lds16(VbB + (size_t)k0 * 2 + voff[b], VsB + lslot[b]);
    }
    __syncthreads();

    f32x4 st[2][4];
#pragma unroll
    for (int i = 0; i < 2; i++)
#pragma unroll
      for (int j = 0; j < 4; j++) st[i][j] = fz;
#pragma unroll
    for (int j = 0; j < 4; j++) {
      int rowk = j * 16 + l16;
#pragma unroll
      for (int t = 0; t < 4; t++) {
        int cc = t * 4 + quad;
        int ch = (cc & 8) | ((cc & 7) ^ (rowk & 7));
        bf16x8 kfr = *(const bf16x8*)(KsB + rowk * 256 + ch * 16);
        st[0][j] = MFMA16(kfr, qf[0][t], st[0][j]);
        st[1][j] = MFMA16(kfr, qf[1][t], st[1][j]);
      }
    }

    const bool do_mask = (kt >= 2 * qt);
#pragma unroll
    for (int i = 0; i < 2; i++) {
      const int qg = q0 + wave * 32 + i * 16 + l16;
      float lacc = 0.f;
#pragma unroll
      for (int j = 0; j < 4; j++) {
        float p[4];
#pragma unroll
        for (int r = 0; r < 4; r++) {
          float v = st[i][j][r];
          if (do_mask && (k0 + j * 16 + quad * 4 + r > qg)) v = -1e30f;
          p[r] = __expf(v);
        }
        lacc += (p[0] + p[1]) + (p[2] + p[3]);
        u16x4 pk = {f2bf(p[0]), f2bf(p[1]), f2bf(p[2]), f2bf(p[3])};
        int prow = wave * 32 + i * 16 + l16;
        *(u16x4*)(PsB + prow * 128 + (((j * 2 + (quad >> 1)) ^ ps_swz) * 16) +
                  (quad & 1) * 8) = pk;
      }
      l_i[i] += lacc;
    }

#pragma unroll
    for (int t = 0; t < 2; t++) {
      int rch = ((t * 4 + quad) ^ ps_swz) * 16;
      bf16x8 af0 = *(const bf16x8*)(PsB + (wave * 32 + l16) * 128 + rch);
      bf16x8 af1 = *(const bf16x8*)(PsB + (wave * 32 + 16 + l16) * 128 + rch);
#pragma unroll
      for (int j = 0; j < 8; j++) {
        int vrow = j * 16 + l16;
        int ch = (t * 4 + quad) ^ (vrow & 7);
        bf16x8 bfr = *(const bf16x8*)(VsB + vrow * 128 + ch * 16);
        o_acc[0][j] = MFMA16(af0, bfr, o_acc[0][j]);
        o_acc[1][j] = MFMA16(af1, bfr, o_acc[1][j]);
      }
    }
  }

  const int bb = bh >> 4, h = bh & 15;
#pragma unroll
  for (int i = 0; i < 2; i++) {
    float rs = l_i[i];
    rs += __shfl_xor(rs, 16);
    rs += __shfl_xor(rs, 32);
    float inv = 1.f / rs;
#pragma unroll
    for (int r = 0; r < 4; r++) {
      float invr = __shfl(inv, (lane & 48) | (quad * 4 + r), 64);
      int srow = q0 + wave * 32 + i * 16 + quad * 4 + r;
      size_t base = ((size_t)(bb * 2048 + srow)) * 2048 + h * 128;
#pragma unroll
      for (int j = 0; j < 8; j++) attn[base + j * 16 + l16] = f2bf(o_acc[i][j][r] * invr);
    }
  }
}

// ---------------------------------------------------------------------------
extern "C" void kernel_launch(void* const* d_in, const int* in_sizes, int n_in,
                              void* d_out, int out_size, void* d_ws, size_t ws_size,
                              hipStream_t stream) {
  (void)n_in; (void)out_size; (void)ws_size;
  const float* x = (const float*)d_in[0];     // [2,2048,2048] f32
  const float* cpq = (const float*)d_in[1];
  const float* cpk = (const float*)d_in[2];
  const float* cpv = (const float*)d_in[3];
  const float* cpo = (const float*)d_in[4];
  float* out = (float*)d_out;
  const int ncp = in_sizes[1];                // 32539
  const double factor = (double)(ncp - 1) / 4194303.0;

  char* ws = (char*)d_ws;
  u16* Wqkv = (u16*)(ws);                  // 6144*2048 bf16 = 25165824 B
  u16* At   = (u16*)(ws);                  // reuses dead Wqkv
  u16* Wo = (u16*)(ws + 25165824);         // 2048*2048 bf16
  u16* Qp = (u16*)(ws + 33554432);         // [B,H,S,D]
  u16* Kp = (u16*)(ws + 50331648);         // [B,H,S,D]
  u16* Vp = (u16*)(ws + 67108864);         // [B,H,D,S]
  u16* xb = (u16*)d_out;                   // [4096,2048] bf16, dead before final GEMM

  prep_kernel<<<dim3(12288), dim3(256), 0, stream>>>(x, cpq, cpk, cpv, cpo, xb, Wqkv, Wo, ncp, factor);
  gemm_qkv<<<dim3(24, 16), dim3(512), 0, stream>>>(xb, Wqkv, Qp, Kp, Vp);
  flash_attn<<<dim3(512), dim3(256), 0, stream>>>(Qp, Kp, Vp, At);
  gemm_bt<1><<<dim3(16, 32), dim3(256), 0, stream>>>(At, Wo, nullptr, nullptr, nullptr, out);
}

// Round 13
// 317.164 us; speedup vs baseline: 1.0613x; 1.0613x over previous
//
#include <hip/hip_runtime.h>
#include <stdint.h>

typedef unsigned short u16;
typedef __bf16 bf16x8 __attribute__((ext_vector_type(8)));
typedef float f32x4 __attribute__((ext_vector_type(4)));
typedef u16 u16x4 __attribute__((ext_vector_type(4)));

#define MFMA16(a, b, c) __builtin_amdgcn_mfma_f32_16x16x32_bf16((a), (b), (c), 0, 0, 0)

__device__ __forceinline__ u16 f2bf(float f) {
  uint32_t u = __builtin_bit_cast(uint32_t, f);
  u += 0x7FFFu + ((u >> 16) & 1u);  // RNE
  return (u16)(u >> 16);
}
__device__ __forceinline__ bf16x8 cvt8(f32x4 lo, f32x4 hi) {
  union { u16 u[8]; bf16x8 v; } r;
#pragma unroll
  for (int j = 0; j < 4; j++) { r.u[j] = f2bf(lo[j]); r.u[4 + j] = f2bf(hi[j]); }
  return r.v;
}
// async global->LDS, 16B per lane. LDS dest = wave-uniform base + lane*16.
__device__ __forceinline__ void gld_lds16(const void* g, void* l) {
  __builtin_amdgcn_global_load_lds(
      (const __attribute__((address_space(1))) uint32_t*)g,
      (__attribute__((address_space(3))) uint32_t*)l, 16, 0, 0);
}

// ---------------------------------------------------------------------------
// Fused prep (R7, proven): weight-interp vectorized 8 samples/thread
// (bf16x8 stores, bit-identical math). Blocks [0,8192): 4 weight curves;
// blocks [8192,12288): x f32->bf16.
// ---------------------------------------------------------------------------
__global__ void prep_kernel(const float* __restrict__ x, const float* __restrict__ cpq,
                            const float* __restrict__ cpk, const float* __restrict__ cpv,
                            const float* __restrict__ cpo, u16* __restrict__ xb,
                            u16* __restrict__ Wqkv, u16* __restrict__ Wo,
                            int n, double factor) {
  int blk = blockIdx.x;
  if (blk < 8192) {
    int base = (blk * 256 + threadIdx.x) * 8;    // < 4*4194304; 8 stay in-curve
    int w = base >> 22;
    int i = base & 4194303;
    const float* cp = (w == 0) ? cpq : (w == 1) ? cpk : (w == 2) ? cpv : cpo;
    union { u16 u[8]; bf16x8 v; } r;
#pragma unroll
    for (int s = 0; s < 8; s++) {
      double u = (double)(i + s) * factor;       // f64: f32 too coarse here
      int i0 = (int)u;
      if (i0 > n - 2) i0 = n - 2;
      float fr = (float)(u - (double)i0);
      float f0 = cp[i0], f1 = cp[i0 + 1];
      r.u[s] = f2bf(f0 + fr * (f1 - f0));
    }
    if (w < 3) *(bf16x8*)(Wqkv + base) = r.v;
    else       *(bf16x8*)(Wo + i) = r.v;
  } else {
    size_t i = ((size_t)(blk - 8192) * 256 + threadIdx.x) * 8;
    const f32x4* p = (const f32x4*)(x + i);
    *(bf16x8*)(xb + i) = cvt8(p[0], p[1]);
  }
}

// ---------------------------------------------------------------------------
// C[M,N] = A[M,2048] @ B[N,2048]^T, bf16 in, f32 acc. 128x128 tile, BK=64.
// PROVEN R0 body, launch_bounds(256,3) (R11 best: 315.2 us total).
// SESSION VERDICT: 44% MfmaUtil = 98% of this structure's LDS-feed cap
// (cap = MFMA_cyc/LDS_cyc, validated on R0/R3/m201). FIVE structurally
// distinct pipelined retiles (R1 BK=32 3buf 155us; R2 128x256 3buf 126;
// R3 +L2map 118; R4 256x384 2buf 118; R12 256x256 8-phase quadrant 146)
// ALL lost to this kernel at 2-3 blocks/CU: occupancy + implicit wave
// overlap (m114) beats every explicit schedule constructible here at
// K=2048 (32 tiles, little prologue amortization). Arc closed.
// MODE 0: scatter bf16 to Q[B,H,S,D] (pre-scaled), K[B,H,S,D], Vt[B,H,D,S]
// MODE 1: row-major f32 [M,2048]
// ---------------------------------------------------------------------------
template <int MODE>
__global__ __launch_bounds__(256, 3)
void gemm_bt(const u16* __restrict__ A, const u16* __restrict__ B,
             u16* __restrict__ oQ, u16* __restrict__ oK, u16* __restrict__ oV,
             float* __restrict__ oC) {
  constexpr int KD = 2048;
  __shared__ __align__(16) u16 As[128 * 64];
  __shared__ __align__(16) u16 Bs[128 * 64];
  const int tid = threadIdx.x;
  const int wave = tid >> 6, lane = tid & 63, quad = lane >> 4, l16 = lane & 15;
  const int wm = wave & 1, wn = wave >> 1;
  const int m0 = blockIdx.y * 128, n0 = blockIdx.x * 128;

  size_t aoff[4], boff[4];
  int lslot[4];
#pragma unroll
  for (int b = 0; b < 4; b++) {
    int s = wave * 256 + b * 64 + lane;  // chunk slot 0..1023 (16B chunks)
    int r = s >> 3, c = s & 7, gc = c ^ (r & 7);
    lslot[b] = s * 16;
    aoff[b] = (size_t)(m0 + r) * (KD * 2) + gc * 16;
    boff[b] = (size_t)(n0 + r) * (KD * 2) + gc * 16;
  }
  const char* Ab = (const char*)A;
  const char* Bb = (const char*)B;
  char* AsB = (char*)As;
  char* BsB = (char*)Bs;

  f32x4 acc[4][4];
  const f32x4 fz = {0.f, 0.f, 0.f, 0.f};
#pragma unroll
  for (int i = 0; i < 4; i++)
#pragma unroll
    for (int j = 0; j < 4; j++) acc[i][j] = fz;

  for (int kt = 0; kt < KD / 64; ++kt) {
    if (kt) __syncthreads();
#pragma unroll
    for (int b = 0; b < 4; b++) {
      gld_lds16(Ab + aoff[b], AsB + lslot[b]);
      gld_lds16(Bb + boff[b], BsB + lslot[b]);
      aoff[b] += 128;
      boff[b] += 128;
    }
    __syncthreads();
#pragma unroll
    for (int t = 0; t < 2; t++) {
      bf16x8 af[4], bfb[4];
#pragma unroll
      for (int i = 0; i < 4; i++) {
        int row = wm * 64 + i * 16 + l16;
        int ch = (t * 4 + quad) ^ (row & 7);
        af[i] = *(const bf16x8*)(AsB + row * 128 + ch * 16);
      }
#pragma unroll
      for (int j = 0; j < 4; j++) {
        int row = wn * 64 + j * 16 + l16;
        int ch = (t * 4 + quad) ^ (row & 7);
        bfb[j] = *(const bf16x8*)(BsB + row * 128 + ch * 16);
      }
#pragma unroll
      for (int i = 0; i < 4; i++)
#pragma unroll
        for (int j = 0; j < 4; j++) acc[i][j] = MFMA16(af[i], bfb[j], acc[i][j]);
    }
  }

  // epilogue: C frag layout col=lane&15 (n), row=quad*4+reg (m)
  if (MODE == 0) {
    const float qscale = 0.08838834764831845f;  // folded into Q
#pragma unroll
    for (int j = 0; j < 4; j++) {
      int nb = n0 + wn * 64 + j * 16;
      int sel = nb >> 11;                      // 0=Q 1=K 2=V
      int h = (nb >> 7) & 15;
      int d = (nb & 127) + l16;
#pragma unroll
      for (int i = 0; i < 4; i++) {
        int mrow = m0 + wm * 64 + i * 16 + quad * 4;
        int bq = mrow >> 11, srow = mrow & 2047;
        if (sel == 2) {
          u16x4 pk = {f2bf(acc[i][j][0]), f2bf(acc[i][j][1]),
                      f2bf(acc[i][j][2]), f2bf(acc[i][j][3])};
          *(u16x4*)&oV[(size_t)(((bq << 4) + h) * 128 + d) * 2048 + srow] = pk;
        } else if (sel == 0) {
          int base = ((bq << 4) + h) * 2048;
#pragma unroll
          for (int r = 0; r < 4; r++)
            oQ[(size_t)(base + srow + r) * 128 + d] = f2bf(acc[i][j][r] * qscale);
        } else {
          int base = ((bq << 4) + h) * 2048;
#pragma unroll
          for (int r = 0; r < 4; r++)
            oK[(size_t)(base + srow + r) * 128 + d] = f2bf(acc[i][j][r]);
        }
      }
    }
  } else {
#pragma unroll
    for (int j = 0; j < 4; j++) {
      int col = n0 + wn * 64 + j * 16 + l16;
#pragma unroll
      for (int i = 0; i < 4; i++) {
        int mrow = m0 + wm * 64 + i * 16 + quad * 4;
#pragma unroll
        for (int r = 0; r < 4; r++) oC[(size_t)(mrow + r) * 2048 + col] = acc[i][j][r];
      }
    }
  }
}

// ---------------------------------------------------------------------------
// Causal flash attention, Bc=64, max-free softmax, TRANSPOSED QK.
// R10-proven body: staged K/V (R9 no-staging exposed L2 latency: 138us,
// reverted), R7 XCD head-grouping (validated: FETCH 24.6MB = compulsory
// traffic), swizzled zero-pad Ps (conflicts 1.67e6 -> ~0). 3 blocks/CU.
// launch_bounds stays (256,2): ~184 unified VGPR > 170 budget for 3/SIMD.
// ---------------------------------------------------------------------------
__global__ __launch_bounds__(256, 2)
void flash_attn(const u16* __restrict__ Q, const u16* __restrict__ Kg,
                const u16* __restrict__ Vt, u16* __restrict__ attn) {
  __shared__ __align__(16) u16 Ks[64 * 128];
  __shared__ __align__(16) u16 Vs[128 * 64];
  __shared__ __align__(16) u16 Ps[128 * 64];
  const int tid = threadIdx.x;
  const int wave = tid >> 6, lane = tid & 63, quad = lane >> 4, l16 = lane & 15;
  const int L = blockIdx.x;
  const int g = L >> 3;
  const int s4 = g >> 2;
  const int qt = (s4 < 8) ? s4 : 23 - s4;
  const int bh = (L & 7) * 4 + (g & 3);
  const int q0 = qt * 128;
  const u16* Qb = Q + (size_t)bh * 2048 * 128;
  const u16* Kb = Kg + (size_t)bh * 2048 * 128;
  const u16* Vb = Vt + (size_t)bh * 128 * 2048;

  // Q B-frags: B[n=lane&15][k=quad*8+j], 2 n-tiles x 4 k-steps (d-chunks)
  bf16x8 qf[2][4];
#pragma unroll
  for (int i = 0; i < 2; i++) {
    int row = q0 + wave * 32 + i * 16 + l16;
#pragma unroll
    for (int t = 0; t < 4; t++)
      qf[i][t] = *(const bf16x8*)(Qb + (size_t)row * 128 + t * 32 + quad * 8);
  }

  f32x4 o_acc[2][8];
  const f32x4 fz = {0.f, 0.f, 0.f, 0.f};
#pragma unroll
  for (int i = 0; i < 2; i++)
#pragma unroll
    for (int j = 0; j < 8; j++) o_acc[i][j] = fz;
  float l_i[2] = {0.f, 0.f};  // per-lane partial row-sum for q = l16 (per i)

  int koff[4], voff[4], lslot[4];
#pragma unroll
  for (int b = 0; b < 4; b++) {
    int s = wave * 256 + b * 64 + lane;  // 0..1023
    lslot[b] = s * 16;
    {  // K-tile: 64 rows x 16 chunks; swizzle low 3 chunk bits by row
      int r = s >> 4, c = s & 15;
      int gc = (c & 8) | ((c & 7) ^ (r & 7));
      koff[b] = r * 256 + gc * 16;
    }
    {  // Vt-tile: 128 rows x 8 chunks (global row stride 4096 B)
      int r = s >> 3, c = s & 7;
      int gc = c ^ (r & 7);
      voff[b] = r * 4096 + gc * 16;
    }
  }
  const char* KbB = (const char*)Kb;
  const char* VbB = (const char*)Vb;
  char* KsB = (char*)Ks;
  char* VsB = (char*)Vs;
  char* PsB = (char*)Ps;
  const int ps_swz = l16 & 7;  // == row&7 for every Ps row this lane touches

  const int ktmax = 2 * qt + 1;

  for (int kt = 0; kt <= ktmax; ++kt) {
    const int k0 = kt * 64;
    if (kt) __syncthreads();
#pragma unroll
    for (int b = 0; b < 4; b++) {
      gld_lds16(KbB + (size_t)k0 * 256 + koff[b], KsB + lslot[b]);
      gld_lds16(VbB + (size_t)k0 * 2 + voff[b], VsB + lslot[b]);
    }
    __syncthreads();

    // S^T = K Q^T : A-frag = K row (contig d), m = k-col; B-frag = Q (regs)
    f32x4 st[2][4];
#pragma unroll
    for (int i = 0; i < 2; i++)
#pragma unroll
      for (int j = 0; j < 4; j++) st[i][j] = fz;
#pragma unroll
    for (int j = 0; j < 4; j++) {
      int rowk = j * 16 + l16;
#pragma unroll
      for (int t = 0; t < 4; t++) {
        int cc = t * 4 + quad;
        int ch = (cc & 8) | ((cc & 7) ^ (rowk & 7));
        bf16x8 kfr = *(const bf16x8*)(KsB + rowk * 256 + ch * 16);
        st[0][j] = MFMA16(kfr, qf[0][t], st[0][j]);
        st[1][j] = MFMA16(kfr, qf[1][t], st[1][j]);
      }
    }

    // max-free softmax; element (k = k0+j*16+quad*4+r, q = q0+wave*32+i*16+l16)
    const bool do_mask = (kt >= 2 * qt);
#pragma unroll
    for (int i = 0; i < 2; i++) {
      const int qg = q0 + wave * 32 + i * 16 + l16;
      float lacc = 0.f;
#pragma unroll
      for (int j = 0; j < 4; j++) {
        float p[4];
#pragma unroll
        for (int r = 0; r < 4; r++) {
          float v = st[i][j][r];
          if (do_mask && (k0 + j * 16 + quad * 4 + r > qg)) v = -1e30f;
          p[r] = __expf(v);  // Q pre-scaled; exp(-1e30) flushes to 0
        }
        lacc += (p[0] + p[1]) + (p[2] + p[3]);
        u16x4 pk = {f2bf(p[0]), f2bf(p[1]), f2bf(p[2]), f2bf(p[3])};
        // swizzled zero-pad store: elems j*16+quad*4.. -> chunk 2j+(quad>>1)
        int prow = wave * 32 + i * 16 + l16;
        *(u16x4*)(PsB + prow * 128 + (((j * 2 + (quad >> 1)) ^ ps_swz) * 16) +
                  (quad & 1) * 8) = pk;
      }
      l_i[i] += lacc;
    }
    // no barrier: each wave reads only its own 32 P rows (in-order DS)

    // O += P V : A-frag from Ps rows (contig k), B-frag = Vt row, n = d-col
#pragma unroll
    for (int t = 0; t < 2; t++) {
      int rch = ((t * 4 + quad) ^ ps_swz) * 16;
      bf16x8 af0 = *(const bf16x8*)(PsB + (wave * 32 + l16) * 128 + rch);
      bf16x8 af1 = *(const bf16x8*)(PsB + (wave * 32 + 16 + l16) * 128 + rch);
#pragma unroll
      for (int j = 0; j < 8; j++) {
        int vrow = j * 16 + l16;
        int ch = (t * 4 + quad) ^ (vrow & 7);
        bf16x8 bfr = *(const bf16x8*)(VsB + vrow * 128 + ch * 16);
        o_acc[0][j] = MFMA16(af0, bfr, o_acc[0][j]);
        o_acc[1][j] = MFMA16(af1, bfr, o_acc[1][j]);
      }
    }
  }

  // epilogue: reduce l over quads (lanes with same l16 hold disjoint k-sets),
  // redistribute to o_acc's row ownership (row = quad*4+r), write.
  const int bb = bh >> 4, h = bh & 15;
#pragma unroll
  for (int i = 0; i < 2; i++) {
    float rs = l_i[i];
    rs += __shfl_xor(rs, 16);
    rs += __shfl_xor(rs, 32);
    float inv = 1.f / rs;  // valid for q-row = i*16 + l16
#pragma unroll
    for (int r = 0; r < 4; r++) {
      float invr = __shfl(inv, (lane & 48) | (quad * 4 + r), 64);
      int srow = q0 + wave * 32 + i * 16 + quad * 4 + r;
      size_t base = ((size_t)(bb * 2048 + srow)) * 2048 + h * 128;
#pragma unroll
      for (int j = 0; j < 8; j++) attn[base + j * 16 + l16] = f2bf(o_acc[i][j][r] * invr);
    }
  }
}

// ---------------------------------------------------------------------------
extern "C" void kernel_launch(void* const* d_in, const int* in_sizes, int n_in,
                              void* d_out, int out_size, void* d_ws, size_t ws_size,
                              hipStream_t stream) {
  (void)n_in; (void)out_size; (void)ws_size;
  const float* x = (const float*)d_in[0];     // [2,2048,2048] f32
  const float* cpq = (const float*)d_in[1];
  const float* cpk = (const float*)d_in[2];
  const float* cpv = (const float*)d_in[3];
  const float* cpo = (const float*)d_in[4];
  // d_in[5] = attention_mask: causal, applied analytically -> unused
  float* out = (float*)d_out;
  const int ncp = in_sizes[1];                // 32539
  const double factor = (double)(ncp - 1) / 4194303.0;

  char* ws = (char*)d_ws;
  u16* Wqkv = (u16*)(ws);                  // 6144*2048 bf16 = 25165824 B
  u16* At   = (u16*)(ws);                  // [B,S,H*D] 16MB, reuses dead Wqkv
  u16* Wo = (u16*)(ws + 25165824);         // 2048*2048 bf16 =  8388608 B
  u16* Qp = (u16*)(ws + 33554432);         // [B,H,S,D] bf16 = 16777216 B
  u16* Kp = (u16*)(ws + 50331648);         // [B,H,S,D]
  u16* Vp = (u16*)(ws + 67108864);         // [B,H,D,S]      (ends 80 MB)
  u16* xb = (u16*)d_out;                   // [4096,2048] bf16, dead before final GEMM

  prep_kernel<<<dim3(12288), dim3(256), 0, stream>>>(x, cpq, cpk, cpv, cpo, xb, Wqkv, Wo, ncp, factor);
  gemm_bt<0><<<dim3(48, 32), dim3(256), 0, stream>>>(xb, Wqkv, Qp, Kp, Vp, nullptr);
  flash_attn<<<dim3(512), dim3(256), 0, stream>>>(Qp, Kp, Vp, At);
  gemm_bt<1><<<dim3(16, 32), dim3(256), 0, stream>>>(At, Wo, nullptr, nullptr, nullptr, out);
}